// Round 6
// baseline (1574.545 us; speedup 1.0000x reference)
//
#include <hip/hip_runtime.h>
#include <hip/hip_bf16.h>
#include <hip/hip_fp16.h>
#include <math.h>

// Problem constants
#define NN 100000
#define EE 1600000
#define ET 1700000            // E + N self-loops
#define NEG_SLOPE 0.2f
#define SCAN_NB 392           // 392*256 = 100352 >= NN
#define NRANGE 8
#define RSIZE 12500           // NN / NRANGE
#define EPT 8                 // edges per thread in range kernels
#define CHUNK (256 * EPT)     // 2048 edges per block
#define NCHUNK ((ET + CHUNK - 1) / CHUNK)
#define XS_STRIDE 136         // 128 + 8 halves: kills LDS bank conflicts

typedef _Float16 f16;
typedef f16 f16x8 __attribute__((ext_vector_type(8)));
typedef float f32x4 __attribute__((ext_vector_type(4)));

__device__ __forceinline__ float leaky(float v) {
    return v > 0.f ? v : NEG_SLOPE * v;
}

__device__ __forceinline__ int xcc_id() {
    unsigned x;
    asm volatile("s_getreg_b32 %0, hwreg(HW_REG_XCC_ID, 0, 32)" : "=s"(x));
    return (int)(x & (NRANGE - 1));
}

// ---------- W1 fp32 [128][64] -> wt fp16 [64][128] (transposed) ----------
__global__ __launch_bounds__(256) void convert_w_kernel(
        const float* __restrict__ W1, f16* __restrict__ wt) {
    int i = blockIdx.x * 256 + threadIdx.x;
    if (i < 128 * 64) {
        int n = i >> 7, k = i & 127;
        wt[n * 128 + k] = (f16)W1[k * 64 + n];
    }
}

// ---------- GEMM1 via MFMA: h1[N,64] = fp16(x[N,128]) @ fp16(W1[128,64]) --
// Block: 64 nodes, 4 waves; wave w -> nodes w*16..w*16+15, all 64 ch.
__global__ __launch_bounds__(256) void gemm1_mfma(
        const float* __restrict__ x, const f16* __restrict__ wt,
        __half* __restrict__ h1) {
    __shared__ f16 xs[64 * XS_STRIDE];
    const int tid = threadIdx.x;
    const int node0 = blockIdx.x * 64;
    // stage x block fp32->fp16 (coalesced float2 per lane)
    for (int i = tid; i < 64 * 64; i += 256) {
        int r = i >> 6, cp = i & 63;
        int n = node0 + r;
        float2 v = (n < NN) ? ((const float2*)x)[(long)n * 64 + cp]
                            : make_float2(0.f, 0.f);
        xs[r * XS_STRIDE + 2 * cp]     = (f16)v.x;
        xs[r * XS_STRIDE + 2 * cp + 1] = (f16)v.y;
    }
    __syncthreads();
    const int wv = tid >> 6;
    const int lane = tid & 63;
    const int n16 = lane & 15;
    const int quad = lane >> 4;
    // B-frags from global wt (16 KB, L1-hot): B[n=lane&15][k=quad*8+j]
    f16x8 bf[4][4];
#pragma unroll
    for (int t = 0; t < 4; ++t)
#pragma unroll
        for (int kk = 0; kk < 4; ++kk)
            bf[t][kk] = *(const f16x8*)(wt + ((t * 16 + n16) * 128 + kk * 32 + quad * 8));
    f32x4 acc[4] = {{0,0,0,0},{0,0,0,0},{0,0,0,0},{0,0,0,0}};
#pragma unroll
    for (int kk = 0; kk < 4; ++kk) {
        f16x8 af = *(const f16x8*)(xs + ((wv * 16 + n16) * XS_STRIDE + kk * 32 + quad * 8));
#pragma unroll
        for (int t = 0; t < 4; ++t)
            acc[t] = __builtin_amdgcn_mfma_f32_16x16x32_f16(af, bf[t][kk], acc[t], 0, 0, 0);
    }
    // D[m = quad*4+reg][ch = t*16+n16]
#pragma unroll
    for (int t = 0; t < 4; ++t)
#pragma unroll
        for (int r = 0; r < 4; ++r) {
            int m = node0 + wv * 16 + quad * 4 + r;
            if (m < NN) h1[(long)m * 64 + t * 16 + n16] = __float2half_rn(acc[t][r]);
        }
}

// ---------- alpha1: per (node, head) dots with att vectors (fp16 h1) ------
__global__ __launch_bounds__(256) void alpha1_kernel(
        const __half* __restrict__ h1, const float* __restrict__ att_s,
        const float* __restrict__ att_d,
        float* __restrict__ alpha_s, float* __restrict__ alpha_d) {
    int i = blockIdx.x * 256 + threadIdx.x;   // i = node*8 + head
    if (i >= NN * 8) return;
    int h = i & 7;
    const __half* hp = h1 + (long)i * 8;
    float s = 0.f, d = 0.f;
#pragma unroll
    for (int c = 0; c < 8; ++c) {
        float v = __half2float(hp[c]);
        s += v * att_s[h * 8 + c];
        d += v * att_d[h * 8 + c];
    }
    alpha_s[i] = s;
    alpha_d[i] = d;
}

// ---------- CSR build: XCC-pinned degree histogram (work-stealing) --------
__global__ __launch_bounds__(256) void deg_hist_kernel(
        const int* __restrict__ ei, int* __restrict__ deg,
        int* __restrict__ ctr) {
    __shared__ int sh_c;
    const int myx = xcc_id();
    for (int rr = 0; rr < NRANGE; ++rr) {
        int r = (myx + rr) & (NRANGE - 1);
        int lo = r * RSIZE, hi = lo + RSIZE;
        while (true) {
            if (threadIdx.x == 0) sh_c = atomicAdd(&ctr[r], 1);
            __syncthreads();
            int c = sh_c;
            __syncthreads();
            if (c >= NCHUNK) break;
            int base = c * CHUNK + threadIdx.x;
#pragma unroll
            for (int k = 0; k < EPT; ++k) {
                int e = base + k * 256;
                if (e >= ET) break;
                int d = (e < EE) ? ei[EE + e] : (e - EE);
                if (d >= lo && d < hi) atomicAdd(&deg[d], 1);
            }
        }
    }
}

// ---------- hierarchical scan phase 1: per-block sums ----------
__global__ __launch_bounds__(256) void scan_phase1(
        const int* __restrict__ deg, int* __restrict__ blocksum) {
    __shared__ int sh[256];
    int t = threadIdx.x;
    int i = blockIdx.x * 256 + t;
    sh[t] = (i < NN) ? deg[i] : 0;
    __syncthreads();
    for (int off = 128; off > 0; off >>= 1) {
        if (t < off) sh[t] += sh[t + off];
        __syncthreads();
    }
    if (t == 0) blocksum[blockIdx.x] = sh[0];
}

// ---------- phase 2: exclusive scan of block sums (1 block) ----------
__global__ __launch_bounds__(512) void scan_phase2(
        const int* __restrict__ blocksum, int* __restrict__ blockoff) {
    __shared__ int sh[512];
    int t = threadIdx.x;
    int v = (t < SCAN_NB) ? blocksum[t] : 0;
    sh[t] = v;
    __syncthreads();
    for (int off = 1; off < 512; off <<= 1) {
        int u = (t >= off) ? sh[t - off] : 0;
        __syncthreads();
        sh[t] += u;
        __syncthreads();
    }
    if (t < SCAN_NB) blockoff[t] = sh[t] - v;   // exclusive
}

// ---------- phase 3: intra-block exclusive scan + offset ----------
__global__ __launch_bounds__(256) void scan_phase3(
        const int* __restrict__ deg, const int* __restrict__ blockoff,
        int* __restrict__ rowptr, int* __restrict__ cursor) {
    __shared__ int sh[256];
    int t = threadIdx.x;
    int i = blockIdx.x * 256 + t;
    int d = (i < NN) ? deg[i] : 0;
    sh[t] = d;
    __syncthreads();
    for (int off = 1; off < 256; off <<= 1) {
        int u = (t >= off) ? sh[t - off] : 0;
        __syncthreads();
        sh[t] += u;
        __syncthreads();
    }
    if (i < NN) {
        int excl = blockoff[blockIdx.x] + sh[t] - d;
        rowptr[i] = excl;
        cursor[i] = excl;
        if (i == NN - 1) rowptr[NN] = excl + d;
    }
}

// ---------- CSR build: XCC-pinned scatter fill (work-stealing) ----------
__global__ __launch_bounds__(256) void csr_fill_kernel(
        const int* __restrict__ ei, int* __restrict__ cursor,
        int* __restrict__ csr_src, int* __restrict__ ctr) {
    __shared__ int sh_c;
    const int myx = xcc_id();
    for (int rr = 0; rr < NRANGE; ++rr) {
        int r = (myx + rr) & (NRANGE - 1);
        int lo = r * RSIZE, hi = lo + RSIZE;
        while (true) {
            if (threadIdx.x == 0) sh_c = atomicAdd(&ctr[r], 1);
            __syncthreads();
            int c = sh_c;
            __syncthreads();
            if (c >= NCHUNK) break;
            int base = c * CHUNK + threadIdx.x;
#pragma unroll
            for (int k = 0; k < EPT; ++k) {
                int e = base + k * 256;
                if (e >= ET) break;
                int s, d;
                if (e < EE) { s = ei[e]; d = ei[EE + e]; } else { s = d = e - EE; }
                if (d >= lo && d < hi) {
                    int pos = atomicAdd(&cursor[d], 1);
                    csr_src[pos] = s;
                }
            }
        }
    }
}

// ---------- conv1 fused: softmax-agg + ReLU/bias + gemm2 + rec pack ------
__global__ __launch_bounds__(256) void conv1_fused_kernel(
        const int* __restrict__ rowptr, const int* __restrict__ csr_src,
        const float* __restrict__ as1, const float* __restrict__ ad1,
        const __half* __restrict__ h1, const float* __restrict__ b1,
        const float* __restrict__ W2, const float* __restrict__ as2,
        const float* __restrict__ ad2, float4* __restrict__ rec) {
    long gid = (long)blockIdx.x * 256 + threadIdx.x;
    int n = (int)(gid >> 6);
    if (n >= NN) return;
    n = __builtin_amdgcn_readfirstlane(n);   // wave-uniform -> scalar loads
    int c = threadIdx.x & 63;
    int h = c >> 3;
    float adh = ad1[n * 8 + h];
    int jb = rowptr[n], je = rowptr[n + 1];
    float l0 = 0.f, l1 = 0.f, l2 = 0.f, l3 = 0.f;
    float a0 = 0.f, a1 = 0.f, a2 = 0.f, a3 = 0.f;
    int j = jb;
    for (; j + 3 < je; j += 4) {
        int s0 = csr_src[j], s1 = csr_src[j + 1];
        int s2 = csr_src[j + 2], s3 = csr_src[j + 3];
        float p0 = __expf(leaky(as1[s0 * 8 + h] + adh));
        float p1 = __expf(leaky(as1[s1 * 8 + h] + adh));
        float p2 = __expf(leaky(as1[s2 * 8 + h] + adh));
        float p3 = __expf(leaky(as1[s3 * 8 + h] + adh));
        l0 += p0; l1 += p1; l2 += p2; l3 += p3;
        a0 += p0 * __half2float(h1[(long)s0 * 64 + c]);
        a1 += p1 * __half2float(h1[(long)s1 * 64 + c]);
        a2 += p2 * __half2float(h1[(long)s2 * 64 + c]);
        a3 += p3 * __half2float(h1[(long)s3 * 64 + c]);
    }
    for (; j < je; ++j) {
        int s = csr_src[j];
        float p = __expf(leaky(as1[s * 8 + h] + adh));
        l0 += p;
        a0 += p * __half2float(h1[(long)s * 64 + c]);
    }
    float l = (l0 + l1) + (l2 + l3);
    float acc = (a0 + a1) + (a2 + a3);
    float o = acc / (l + 1e-16f);
    float a = o + b1[c];
    a = a > 0.f ? a : 0.f;                 // ReLU
    float r0 = a * W2[c * 2];
    float r1 = a * W2[c * 2 + 1];
#pragma unroll
    for (int off = 32; off > 0; off >>= 1) {
        r0 += __shfl_xor(r0, off, 64);
        r1 += __shfl_xor(r1, off, 64);
    }
    if (c == 0) {
        float s2v = r0 * as2[0] + r1 * as2[1];
        float d2v = r0 * ad2[0] + r1 * ad2[1];
        rec[n] = make_float4(s2v, r0, r1, d2v);   // (as2o, h2_0, h2_1, ad2o)
    }
}

// ---------- conv2 fused with mean-pool (LDS partials) ----------
__global__ __launch_bounds__(256) void conv2_pool_kernel(
        const int* __restrict__ rowptr, const int* __restrict__ csr_src,
        const float4* __restrict__ rec, const int* __restrict__ batch,
        float* __restrict__ pooled /*128 sums + 64 counts*/) {
    __shared__ float ls[192];
    int tid = threadIdx.x;
    if (tid < 192) ls[tid] = 0.f;
    __syncthreads();
    int n = blockIdx.x * 256 + tid;
    if (n < NN) {
        float adn = rec[n].w;
        int jb = rowptr[n], je = rowptr[n + 1];
        float l0 = 0.f, l1 = 0.f, x0 = 0.f, x1 = 0.f, y0 = 0.f, y1 = 0.f;
        int j = jb;
        for (; j + 1 < je; j += 2) {
            float4 ra = rec[csr_src[j]];
            float4 rb = rec[csr_src[j + 1]];
            float pa = __expf(leaky(ra.x + adn));
            float pb = __expf(leaky(rb.x + adn));
            l0 += pa; x0 += pa * ra.y; y0 += pa * ra.z;
            l1 += pb; x1 += pb * rb.y; y1 += pb * rb.z;
        }
        for (; j < je; ++j) {
            float4 ra = rec[csr_src[j]];
            float pa = __expf(leaky(ra.x + adn));
            l0 += pa; x0 += pa * ra.y; y0 += pa * ra.z;
        }
        float inv = 1.f / (l0 + l1 + 1e-16f);
        int g = batch[n];
        atomicAdd(&ls[g * 2],     (x0 + x1) * inv);
        atomicAdd(&ls[g * 2 + 1], (y0 + y1) * inv);
        atomicAdd(&ls[128 + g],   1.f);
    }
    __syncthreads();
    if (tid < 192) atomicAdd(&pooled[tid], ls[tid]);
}

// ---------- finalize: mean, +b2, log_softmax ----------
__global__ __launch_bounds__(64) void final_kernel(
        const float* __restrict__ pooled, const float* __restrict__ b2,
        float* __restrict__ out) {
    int g = threadIdx.x;
    if (g >= 64) return;
    float c = pooled[128 + g];
    float denom = c > 1.f ? c : 1.f;
    float p0 = pooled[g * 2] / denom + b2[0];
    float p1 = pooled[g * 2 + 1] / denom + b2[1];
    float m = fmaxf(p0, p1);
    float lse = m + logf(expf(p0 - m) + expf(p1 - m));
    out[g * 2] = p0 - lse;
    out[g * 2 + 1] = p1 - lse;
}

extern "C" void kernel_launch(void* const* d_in, const int* in_sizes, int n_in,
                              void* d_out, int out_size, void* d_ws, size_t ws_size,
                              hipStream_t stream) {
    const float* x   = (const float*)d_in[0];
    const int*   ei  = (const int*)d_in[1];     // [2,E] int32
    const int*   bat = (const int*)d_in[2];     // [N]
    const float* W1  = (const float*)d_in[3];
    const float* as1 = (const float*)d_in[4];
    const float* ad1 = (const float*)d_in[5];
    const float* b1  = (const float*)d_in[6];
    const float* W2  = (const float*)d_in[7];
    const float* as2 = (const float*)d_in[8];
    const float* ad2 = (const float*)d_in[9];
    const float* b2  = (const float*)d_in[10];
    float* out = (float*)d_out;

    float* ws = (float*)d_ws;
    // workspace layout (element offsets; 16B-aligned where needed)
    const long off_h1     = 0;                          // N*64 halves = N*32 f
    const long off_wt     = off_h1   + (long)NN * 32;   // 8192 halves = 4096 f
    const long off_as1    = off_wt   + 4096;            // N*8
    const long off_ad1    = off_as1  + (long)NN * 8;    // N*8
    const long off_rec    = off_ad1  + (long)NN * 8;    // N*4 (float4)
    const long off_rowptr = off_rec  + (long)NN * 4;    // N+1 (int)
    const long off_cursor = off_rowptr + NN + 1;        // N   (int)
    const long off_csr    = off_cursor + NN;            // ET  (int)
    const long off_bsum   = off_csr + ET;               // SCAN_NB (int)
    const long off_boff   = off_bsum + SCAN_NB;         // SCAN_NB (int)
    const long off_zero   = off_boff + SCAN_NB;         // ---- zeroed ----
    const long off_deg    = off_zero;                   // N   (int)
    const long off_pool   = off_deg + NN;               // 192
    const long off_ctrA   = off_pool + 192;             // 8 (int)
    const long off_ctrB   = off_ctrA + 8;               // 8 (int)
    const long zero_elems = off_ctrB + 8 - off_zero;

    hipMemsetAsync(ws + off_zero, 0, zero_elems * sizeof(float), stream);

    convert_w_kernel<<<32, 256, 0, stream>>>(W1, (f16*)(ws + off_wt));
    gemm1_mfma<<<(NN + 63) / 64, 256, 0, stream>>>(
        x, (const f16*)(ws + off_wt), (__half*)(ws + off_h1));
    alpha1_kernel<<<(NN * 8 + 255) / 256, 256, 0, stream>>>(
        (const __half*)(ws + off_h1), as1, ad1, ws + off_as1, ws + off_ad1);

    const int rb = NCHUNK * NRANGE;
    deg_hist_kernel<<<rb, 256, 0, stream>>>(ei, (int*)(ws + off_deg),
                                            (int*)(ws + off_ctrA));
    scan_phase1<<<SCAN_NB, 256, 0, stream>>>((const int*)(ws + off_deg),
                                             (int*)(ws + off_bsum));
    scan_phase2<<<1, 512, 0, stream>>>((const int*)(ws + off_bsum),
                                       (int*)(ws + off_boff));
    scan_phase3<<<SCAN_NB, 256, 0, stream>>>((const int*)(ws + off_deg),
                                             (const int*)(ws + off_boff),
                                             (int*)(ws + off_rowptr),
                                             (int*)(ws + off_cursor));
    csr_fill_kernel<<<rb, 256, 0, stream>>>(ei, (int*)(ws + off_cursor),
                                            (int*)(ws + off_csr),
                                            (int*)(ws + off_ctrB));

    conv1_fused_kernel<<<(int)(((long)NN * 64 + 255) / 256), 256, 0, stream>>>(
        (const int*)(ws + off_rowptr), (const int*)(ws + off_csr),
        ws + off_as1, ws + off_ad1, (const __half*)(ws + off_h1), b1, W2,
        as2, ad2, (float4*)(ws + off_rec));

    conv2_pool_kernel<<<(NN + 255) / 256, 256, 0, stream>>>(
        (const int*)(ws + off_rowptr), (const int*)(ws + off_csr),
        (const float4*)(ws + off_rec), bat, ws + off_pool);

    final_kernel<<<1, 64, 0, stream>>>(ws + off_pool, b2, out);
}

// Round 7
// 381.554 us; speedup vs baseline: 4.1267x; 4.1267x over previous
//
#include <hip/hip_runtime.h>
#include <hip/hip_bf16.h>
#include <hip/hip_fp16.h>
#include <math.h>

// Problem constants
#define NN 100000
#define EE 1600000
#define ET 1700000            // E + N self-loops
#define NEG_SLOPE 0.2f
#define SCAN_NB 392           // 392*256 = 100352 >= NN
#define NRANGE 8
#define RSIZE 12500           // NN / NRANGE
#define EPT 8                 // edges per thread in range kernels
#define CHUNK (256 * EPT)     // 2048 edges per block
#define NCHUNK ((ET + CHUNK - 1) / CHUNK)
#define XS_STRIDE 136         // 128 + 8 halves: kills LDS bank conflicts

typedef _Float16 f16;
typedef f16 f16x8 __attribute__((ext_vector_type(8)));
typedef float f32x4 __attribute__((ext_vector_type(4)));

__device__ __forceinline__ float leaky(float v) {
    return v > 0.f ? v : NEG_SLOPE * v;
}

// ---------- W1 fp32 [128][64] -> wt fp16 [64][128] (transposed) ----------
__global__ __launch_bounds__(256) void convert_w_kernel(
        const float* __restrict__ W1, f16* __restrict__ wt) {
    int i = blockIdx.x * 256 + threadIdx.x;
    if (i < 128 * 64) {
        int n = i >> 7, k = i & 127;
        wt[n * 128 + k] = (f16)W1[k * 64 + n];
    }
}

// ---------- GEMM1 via MFMA: h1[N,64] = fp16(x[N,128]) @ fp16(W1[128,64]) --
// Block: 64 nodes, 4 waves; wave w -> nodes w*16..w*16+15, all 64 ch.
__global__ __launch_bounds__(256) void gemm1_mfma(
        const float* __restrict__ x, const f16* __restrict__ wt,
        __half* __restrict__ h1) {
    __shared__ f16 xs[64 * XS_STRIDE];
    const int tid = threadIdx.x;
    const int node0 = blockIdx.x * 64;
    for (int i = tid; i < 64 * 64; i += 256) {
        int r = i >> 6, cp = i & 63;
        int n = node0 + r;
        float2 v = (n < NN) ? ((const float2*)x)[(long)n * 64 + cp]
                            : make_float2(0.f, 0.f);
        xs[r * XS_STRIDE + 2 * cp]     = (f16)v.x;
        xs[r * XS_STRIDE + 2 * cp + 1] = (f16)v.y;
    }
    __syncthreads();
    const int wv = tid >> 6;
    const int lane = tid & 63;
    const int n16 = lane & 15;
    const int quad = lane >> 4;
    f16x8 bf[4][4];
#pragma unroll
    for (int t = 0; t < 4; ++t)
#pragma unroll
        for (int kk = 0; kk < 4; ++kk)
            bf[t][kk] = *(const f16x8*)(wt + ((t * 16 + n16) * 128 + kk * 32 + quad * 8));
    f32x4 acc[4] = {{0,0,0,0},{0,0,0,0},{0,0,0,0},{0,0,0,0}};
#pragma unroll
    for (int kk = 0; kk < 4; ++kk) {
        f16x8 af = *(const f16x8*)(xs + ((wv * 16 + n16) * XS_STRIDE + kk * 32 + quad * 8));
#pragma unroll
        for (int t = 0; t < 4; ++t)
            acc[t] = __builtin_amdgcn_mfma_f32_16x16x32_f16(af, bf[t][kk], acc[t], 0, 0, 0);
    }
    // D[m = quad*4+reg][ch = t*16+n16]
#pragma unroll
    for (int t = 0; t < 4; ++t)
#pragma unroll
        for (int r = 0; r < 4; ++r) {
            int m = node0 + wv * 16 + quad * 4 + r;
            if (m < NN) h1[(long)m * 64 + t * 16 + n16] = __float2half_rn(acc[t][r]);
        }
}

// ---------- alpha1: per (node, head) dots with att vectors (fp16 h1) ------
__global__ __launch_bounds__(256) void alpha1_kernel(
        const __half* __restrict__ h1, const float* __restrict__ att_s,
        const float* __restrict__ att_d,
        float* __restrict__ alpha_s, float* __restrict__ alpha_d) {
    int i = blockIdx.x * 256 + threadIdx.x;   // i = node*8 + head
    if (i >= NN * 8) return;
    int h = i & 7;
    const __half* hp = h1 + (long)i * 8;
    float s = 0.f, d = 0.f;
#pragma unroll
    for (int c = 0; c < 8; ++c) {
        float v = __half2float(hp[c]);
        s += v * att_s[h * 8 + c];
        d += v * att_d[h * 8 + c];
    }
    alpha_s[i] = s;
    alpha_d[i] = d;
}

// ---------- CSR build: dst-range-partitioned degree histogram ----------
// blockIdx%8 ~ XCD round-robin; ei reads non-temporal (don't thrash L2).
__global__ __launch_bounds__(256) void deg_hist_kernel(
        const int* __restrict__ ei, int* __restrict__ deg) {
    const int range = blockIdx.x & (NRANGE - 1);
    const int chunk = blockIdx.x >> 3;
    const int lo = range * RSIZE, hi = lo + RSIZE;
    const int base = chunk * CHUNK + threadIdx.x;
#pragma unroll
    for (int k = 0; k < EPT; ++k) {
        int e = base + k * 256;
        if (e >= ET) break;
        int d = (e < EE) ? __builtin_nontemporal_load(ei + EE + e) : (e - EE);
        if (d >= lo && d < hi) atomicAdd(&deg[d], 1);
    }
}

// ---------- hierarchical scan phase 1: per-block sums ----------
__global__ __launch_bounds__(256) void scan_phase1(
        const int* __restrict__ deg, int* __restrict__ blocksum) {
    __shared__ int sh[256];
    int t = threadIdx.x;
    int i = blockIdx.x * 256 + t;
    sh[t] = (i < NN) ? deg[i] : 0;
    __syncthreads();
    for (int off = 128; off > 0; off >>= 1) {
        if (t < off) sh[t] += sh[t + off];
        __syncthreads();
    }
    if (t == 0) blocksum[blockIdx.x] = sh[0];
}

// ---------- phase 2: exclusive scan of block sums (1 block) ----------
__global__ __launch_bounds__(512) void scan_phase2(
        const int* __restrict__ blocksum, int* __restrict__ blockoff) {
    __shared__ int sh[512];
    int t = threadIdx.x;
    int v = (t < SCAN_NB) ? blocksum[t] : 0;
    sh[t] = v;
    __syncthreads();
    for (int off = 1; off < 512; off <<= 1) {
        int u = (t >= off) ? sh[t - off] : 0;
        __syncthreads();
        sh[t] += u;
        __syncthreads();
    }
    if (t < SCAN_NB) blockoff[t] = sh[t] - v;   // exclusive
}

// ---------- phase 3: intra-block exclusive scan + offset ----------
__global__ __launch_bounds__(256) void scan_phase3(
        const int* __restrict__ deg, const int* __restrict__ blockoff,
        int* __restrict__ rowptr, int* __restrict__ cursor) {
    __shared__ int sh[256];
    int t = threadIdx.x;
    int i = blockIdx.x * 256 + t;
    int d = (i < NN) ? deg[i] : 0;
    sh[t] = d;
    __syncthreads();
    for (int off = 1; off < 256; off <<= 1) {
        int u = (t >= off) ? sh[t - off] : 0;
        __syncthreads();
        sh[t] += u;
        __syncthreads();
    }
    if (i < NN) {
        int excl = blockoff[blockIdx.x] + sh[t] - d;
        rowptr[i] = excl;
        cursor[i] = excl;
        if (i == NN - 1) rowptr[NN] = excl + d;
    }
}

// ---------- CSR build: dst-range-partitioned scatter fill ----------
__global__ __launch_bounds__(256) void csr_fill_kernel(
        const int* __restrict__ ei, int* __restrict__ cursor,
        int* __restrict__ csr_src) {
    const int range = blockIdx.x & (NRANGE - 1);
    const int chunk = blockIdx.x >> 3;
    const int lo = range * RSIZE, hi = lo + RSIZE;
    const int base = chunk * CHUNK + threadIdx.x;
#pragma unroll
    for (int k = 0; k < EPT; ++k) {
        int e = base + k * 256;
        if (e >= ET) break;
        int s, d;
        if (e < EE) {
            s = __builtin_nontemporal_load(ei + e);
            d = __builtin_nontemporal_load(ei + EE + e);
        } else { s = d = e - EE; }
        if (d >= lo && d < hi) {
            int pos = atomicAdd(&cursor[d], 1);
            csr_src[pos] = s;
        }
    }
}

// ---------- conv1 fused: softmax-agg + ReLU/bias + gemm2 + rec pack ------
__global__ __launch_bounds__(256) void conv1_fused_kernel(
        const int* __restrict__ rowptr, const int* __restrict__ csr_src,
        const float* __restrict__ as1, const float* __restrict__ ad1,
        const __half* __restrict__ h1, const float* __restrict__ b1,
        const float* __restrict__ W2, const float* __restrict__ as2,
        const float* __restrict__ ad2, float4* __restrict__ rec) {
    long gid = (long)blockIdx.x * 256 + threadIdx.x;
    int n = (int)(gid >> 6);
    if (n >= NN) return;
    n = __builtin_amdgcn_readfirstlane(n);   // wave-uniform -> scalar loads
    int c = threadIdx.x & 63;
    int h = c >> 3;
    float adh = ad1[n * 8 + h];
    int jb = rowptr[n], je = rowptr[n + 1];
    float l0 = 0.f, l1 = 0.f, l2 = 0.f, l3 = 0.f;
    float a0 = 0.f, a1 = 0.f, a2 = 0.f, a3 = 0.f;
    int j = jb;
    for (; j + 3 < je; j += 4) {
        int s0 = csr_src[j], s1 = csr_src[j + 1];
        int s2 = csr_src[j + 2], s3 = csr_src[j + 3];
        float p0 = __expf(leaky(as1[s0 * 8 + h] + adh));
        float p1 = __expf(leaky(as1[s1 * 8 + h] + adh));
        float p2 = __expf(leaky(as1[s2 * 8 + h] + adh));
        float p3 = __expf(leaky(as1[s3 * 8 + h] + adh));
        l0 += p0; l1 += p1; l2 += p2; l3 += p3;
        a0 += p0 * __half2float(h1[(long)s0 * 64 + c]);
        a1 += p1 * __half2float(h1[(long)s1 * 64 + c]);
        a2 += p2 * __half2float(h1[(long)s2 * 64 + c]);
        a3 += p3 * __half2float(h1[(long)s3 * 64 + c]);
    }
    for (; j < je; ++j) {
        int s = csr_src[j];
        float p = __expf(leaky(as1[s * 8 + h] + adh));
        l0 += p;
        a0 += p * __half2float(h1[(long)s * 64 + c]);
    }
    float l = (l0 + l1) + (l2 + l3);
    float acc = (a0 + a1) + (a2 + a3);
    float o = acc / (l + 1e-16f);
    float a = o + b1[c];
    a = a > 0.f ? a : 0.f;                 // ReLU
    float r0 = a * W2[c * 2];
    float r1 = a * W2[c * 2 + 1];
#pragma unroll
    for (int off = 32; off > 0; off >>= 1) {
        r0 += __shfl_xor(r0, off, 64);
        r1 += __shfl_xor(r1, off, 64);
    }
    if (c == 0) {
        float s2v = r0 * as2[0] + r1 * as2[1];
        float d2v = r0 * ad2[0] + r1 * ad2[1];
        rec[n] = make_float4(s2v, r0, r1, d2v);   // (as2o, h2_0, h2_1, ad2o)
    }
}

// ---------- conv2 fused with mean-pool (LDS partials) ----------
__global__ __launch_bounds__(256) void conv2_pool_kernel(
        const int* __restrict__ rowptr, const int* __restrict__ csr_src,
        const float4* __restrict__ rec, const int* __restrict__ batch,
        float* __restrict__ pooled /*128 sums + 64 counts*/) {
    __shared__ float ls[192];
    int tid = threadIdx.x;
    if (tid < 192) ls[tid] = 0.f;
    __syncthreads();
    int n = blockIdx.x * 256 + tid;
    if (n < NN) {
        float adn = rec[n].w;
        int jb = rowptr[n], je = rowptr[n + 1];
        float l0 = 0.f, l1 = 0.f, x0 = 0.f, x1 = 0.f, y0 = 0.f, y1 = 0.f;
        int j = jb;
        for (; j + 1 < je; j += 2) {
            float4 ra = rec[csr_src[j]];
            float4 rb = rec[csr_src[j + 1]];
            float pa = __expf(leaky(ra.x + adn));
            float pb = __expf(leaky(rb.x + adn));
            l0 += pa; x0 += pa * ra.y; y0 += pa * ra.z;
            l1 += pb; x1 += pb * rb.y; y1 += pb * rb.z;
        }
        for (; j < je; ++j) {
            float4 ra = rec[csr_src[j]];
            float pa = __expf(leaky(ra.x + adn));
            l0 += pa; x0 += pa * ra.y; y0 += pa * ra.z;
        }
        float inv = 1.f / (l0 + l1 + 1e-16f);
        int g = batch[n];
        atomicAdd(&ls[g * 2],     (x0 + x1) * inv);
        atomicAdd(&ls[g * 2 + 1], (y0 + y1) * inv);
        atomicAdd(&ls[128 + g],   1.f);
    }
    __syncthreads();
    if (tid < 192) atomicAdd(&pooled[tid], ls[tid]);
}

// ---------- finalize: mean, +b2, log_softmax ----------
__global__ __launch_bounds__(64) void final_kernel(
        const float* __restrict__ pooled, const float* __restrict__ b2,
        float* __restrict__ out) {
    int g = threadIdx.x;
    if (g >= 64) return;
    float c = pooled[128 + g];
    float denom = c > 1.f ? c : 1.f;
    float p0 = pooled[g * 2] / denom + b2[0];
    float p1 = pooled[g * 2 + 1] / denom + b2[1];
    float m = fmaxf(p0, p1);
    float lse = m + logf(expf(p0 - m) + expf(p1 - m));
    out[g * 2] = p0 - lse;
    out[g * 2 + 1] = p1 - lse;
}

extern "C" void kernel_launch(void* const* d_in, const int* in_sizes, int n_in,
                              void* d_out, int out_size, void* d_ws, size_t ws_size,
                              hipStream_t stream) {
    const float* x   = (const float*)d_in[0];
    const int*   ei  = (const int*)d_in[1];     // [2,E] int32
    const int*   bat = (const int*)d_in[2];     // [N]
    const float* W1  = (const float*)d_in[3];
    const float* as1 = (const float*)d_in[4];
    const float* ad1 = (const float*)d_in[5];
    const float* b1  = (const float*)d_in[6];
    const float* W2  = (const float*)d_in[7];
    const float* as2 = (const float*)d_in[8];
    const float* ad2 = (const float*)d_in[9];
    const float* b2  = (const float*)d_in[10];
    float* out = (float*)d_out;

    float* ws = (float*)d_ws;
    // workspace layout (element offsets; 16B-aligned where needed)
    const long off_h1     = 0;                          // N*64 halves = N*32 f
    const long off_wt     = off_h1   + (long)NN * 32;   // 8192 halves = 4096 f
    const long off_as1    = off_wt   + 4096;            // N*8
    const long off_ad1    = off_as1  + (long)NN * 8;    // N*8
    const long off_rec    = off_ad1  + (long)NN * 8;    // N*4 (float4)
    const long off_rowptr = off_rec  + (long)NN * 4;    // N+1 (int)
    const long off_cursor = off_rowptr + NN + 1;        // N   (int)
    const long off_csr    = off_cursor + NN;            // ET  (int)
    const long off_bsum   = off_csr + ET;               // SCAN_NB (int)
    const long off_boff   = off_bsum + SCAN_NB;         // SCAN_NB (int)
    const long off_zero   = off_boff + SCAN_NB;         // ---- zeroed ----
    const long off_deg    = off_zero;                   // N   (int)
    const long off_pool   = off_deg + NN;               // 192
    const long zero_elems = off_pool + 192 - off_zero;

    hipMemsetAsync(ws + off_zero, 0, zero_elems * sizeof(float), stream);

    convert_w_kernel<<<32, 256, 0, stream>>>(W1, (f16*)(ws + off_wt));
    gemm1_mfma<<<(NN + 63) / 64, 256, 0, stream>>>(
        x, (const f16*)(ws + off_wt), (__half*)(ws + off_h1));
    alpha1_kernel<<<(NN * 8 + 255) / 256, 256, 0, stream>>>(
        (const __half*)(ws + off_h1), as1, ad1, ws + off_as1, ws + off_ad1);

    const int rb = NCHUNK * NRANGE;
    deg_hist_kernel<<<rb, 256, 0, stream>>>(ei, (int*)(ws + off_deg));
    scan_phase1<<<SCAN_NB, 256, 0, stream>>>((const int*)(ws + off_deg),
                                             (int*)(ws + off_bsum));
    scan_phase2<<<1, 512, 0, stream>>>((const int*)(ws + off_bsum),
                                       (int*)(ws + off_boff));
    scan_phase3<<<SCAN_NB, 256, 0, stream>>>((const int*)(ws + off_deg),
                                             (const int*)(ws + off_boff),
                                             (int*)(ws + off_rowptr),
                                             (int*)(ws + off_cursor));
    csr_fill_kernel<<<rb, 256, 0, stream>>>(ei, (int*)(ws + off_cursor),
                                            (int*)(ws + off_csr));

    conv1_fused_kernel<<<(int)(((long)NN * 64 + 255) / 256), 256, 0, stream>>>(
        (const int*)(ws + off_rowptr), (const int*)(ws + off_csr),
        ws + off_as1, ws + off_ad1, (const __half*)(ws + off_h1), b1, W2,
        as2, ad2, (float4*)(ws + off_rec));

    conv2_pool_kernel<<<(NN + 255) / 256, 256, 0, stream>>>(
        (const int*)(ws + off_rowptr), (const int*)(ws + off_csr),
        (const float4*)(ws + off_rec), bat, ws + off_pool);

    final_kernel<<<1, 64, 0, stream>>>(ws + off_pool, b2, out);
}

// Round 8
// 336.189 us; speedup vs baseline: 4.6835x; 1.1349x over previous
//
#include <hip/hip_runtime.h>
#include <hip/hip_bf16.h>
#include <hip/hip_fp16.h>
#include <math.h>

// Problem constants
#define NN 100000
#define EE 1600000
#define ET 1700000            // E + N self-loops
#define NEG_SLOPE 0.2f
#define XS_STRIDE 136         // 128 + 8 halves: kills LDS bank conflicts

// bucket-sort CSR build
#define BKB 11                // log2(dsts per bucket)
#define BKSZ 2048
#define NBUCK 49              // ceil(NN / BKSZ)
#define SUBN 4                // sub-blocks per bucket in fine_csr (512-slices)
#define PAD 32                // ints per counter (one 128B line each)
#define EPT2 16
#define CHUNK2 (256 * EPT2)   // 4096 edges per block
#define NCH2 ((ET + CHUNK2 - 1) / CHUNK2)   // 416

typedef _Float16 f16;
typedef f16 f16x8 __attribute__((ext_vector_type(8)));
typedef float f32x4 __attribute__((ext_vector_type(4)));

__device__ __forceinline__ float leaky(float v) {
    return v > 0.f ? v : NEG_SLOPE * v;
}

// ---------- W1 fp32 [128][64] -> wt fp16 [64][128] (transposed) ----------
__global__ __launch_bounds__(256) void convert_w_kernel(
        const float* __restrict__ W1, f16* __restrict__ wt) {
    int i = blockIdx.x * 256 + threadIdx.x;
    if (i < 128 * 64) {
        int n = i >> 7, k = i & 127;
        wt[n * 128 + k] = (f16)W1[k * 64 + n];
    }
}

// ---------- GEMM1 via MFMA ----------
__global__ __launch_bounds__(256) void gemm1_mfma(
        const float* __restrict__ x, const f16* __restrict__ wt,
        __half* __restrict__ h1) {
    __shared__ f16 xs[64 * XS_STRIDE];
    const int tid = threadIdx.x;
    const int node0 = blockIdx.x * 64;
    for (int i = tid; i < 64 * 64; i += 256) {
        int r = i >> 6, cp = i & 63;
        int n = node0 + r;
        float2 v = (n < NN) ? ((const float2*)x)[(long)n * 64 + cp]
                            : make_float2(0.f, 0.f);
        xs[r * XS_STRIDE + 2 * cp]     = (f16)v.x;
        xs[r * XS_STRIDE + 2 * cp + 1] = (f16)v.y;
    }
    __syncthreads();
    const int wv = tid >> 6;
    const int lane = tid & 63;
    const int n16 = lane & 15;
    const int quad = lane >> 4;
    f16x8 bf[4][4];
#pragma unroll
    for (int t = 0; t < 4; ++t)
#pragma unroll
        for (int kk = 0; kk < 4; ++kk)
            bf[t][kk] = *(const f16x8*)(wt + ((t * 16 + n16) * 128 + kk * 32 + quad * 8));
    f32x4 acc[4] = {{0,0,0,0},{0,0,0,0},{0,0,0,0},{0,0,0,0}};
#pragma unroll
    for (int kk = 0; kk < 4; ++kk) {
        f16x8 af = *(const f16x8*)(xs + ((wv * 16 + n16) * XS_STRIDE + kk * 32 + quad * 8));
#pragma unroll
        for (int t = 0; t < 4; ++t)
            acc[t] = __builtin_amdgcn_mfma_f32_16x16x32_f16(af, bf[t][kk], acc[t], 0, 0, 0);
    }
#pragma unroll
    for (int t = 0; t < 4; ++t)
#pragma unroll
        for (int r = 0; r < 4; ++r) {
            int m = node0 + wv * 16 + quad * 4 + r;
            if (m < NN) h1[(long)m * 64 + t * 16 + n16] = __float2half_rn(acc[t][r]);
        }
}

// ---------- alpha1 ----------
__global__ __launch_bounds__(256) void alpha1_kernel(
        const __half* __restrict__ h1, const float* __restrict__ att_s,
        const float* __restrict__ att_d,
        float* __restrict__ alpha_s, float* __restrict__ alpha_d) {
    int i = blockIdx.x * 256 + threadIdx.x;   // i = node*8 + head
    if (i >= NN * 8) return;
    int h = i & 7;
    const __half* hp = h1 + (long)i * 8;
    float s = 0.f, d = 0.f;
#pragma unroll
    for (int c = 0; c < 8; ++c) {
        float v = __half2float(hp[c]);
        s += v * att_s[h * 8 + c];
        d += v * att_d[h * 8 + c];
    }
    alpha_s[i] = s;
    alpha_d[i] = d;
}

// ---------- B1: coarse bucket count (LDS hist -> padded global atomics) ---
__global__ __launch_bounds__(256) void bucket_count(
        const int* __restrict__ ei, int* __restrict__ bcnt) {
    __shared__ int lcnt[NBUCK];
    const int tid = threadIdx.x;
    for (int i = tid; i < NBUCK; i += 256) lcnt[i] = 0;
    __syncthreads();
    const int base = blockIdx.x * CHUNK2 + tid;
#pragma unroll
    for (int k = 0; k < EPT2; ++k) {
        int e = base + k * 256;
        if (e >= ET) break;
        int d = (e < EE) ? __builtin_nontemporal_load(ei + EE + e) : (e - EE);
        atomicAdd(&lcnt[d >> BKB], 1);
    }
    __syncthreads();
    if (tid < NBUCK) atomicAdd(&bcnt[tid * PAD], lcnt[tid]);
}

// ---------- B2: exclusive scan of 49 bucket counts (1 wave) ----------
__global__ __launch_bounds__(64) void bucket_scan(
        const int* __restrict__ bcnt, int* __restrict__ boff,
        int* __restrict__ bcur) {
    int t = threadIdx.x;
    int v = (t < NBUCK) ? bcnt[t * PAD] : 0;
    int incl = v;
#pragma unroll
    for (int off = 1; off < 64; off <<= 1) {
        int u = __shfl_up(incl, off, 64);
        if (t >= off) incl += u;
    }
    if (t < NBUCK) {
        boff[t] = incl - v;
        bcur[t * PAD] = incl - v;
        if (t == NBUCK - 1) boff[NBUCK] = incl;
    }
}

// ---------- B3: bucket fill — packed payload rel<<17|src ----------
__global__ __launch_bounds__(256) void bucket_fill(
        const int* __restrict__ ei, int* __restrict__ bcur,
        unsigned* __restrict__ gpay) {
    __shared__ int lcnt[NBUCK];
    __shared__ int gbase[NBUCK];
    const int tid = threadIdx.x;
    for (int i = tid; i < NBUCK; i += 256) lcnt[i] = 0;
    __syncthreads();
    const int base = blockIdx.x * CHUNK2 + tid;
    unsigned pay[EPT2];
    int bk[EPT2], pos[EPT2];
#pragma unroll
    for (int k = 0; k < EPT2; ++k) {
        int e = base + k * 256;
        if (e < ET) {
            int s, d;
            if (e < EE) {
                s = __builtin_nontemporal_load(ei + e);
                d = __builtin_nontemporal_load(ei + EE + e);
            } else { s = d = e - EE; }
            int b = d >> BKB;
            bk[k] = b;
            pay[k] = ((unsigned)(d & (BKSZ - 1)) << 17) | (unsigned)s;
            pos[k] = atomicAdd(&lcnt[b], 1);
        } else bk[k] = -1;
    }
    __syncthreads();
    if (tid < NBUCK) gbase[tid] = atomicAdd(&bcur[tid * PAD], lcnt[tid]);
    __syncthreads();
#pragma unroll
    for (int k = 0; k < EPT2; ++k)
        if (bk[k] >= 0) gpay[gbase[bk[k]] + pos[k]] = pay[k];
}

// ---------- B4: fine CSR within each bucket (LDS hist+scan+cursors) -------
// grid = NBUCK*SUBN; block (b,sub) scatters rel-slice [sub*512,(sub+1)*512).
__global__ __launch_bounds__(256) void fine_csr(
        const unsigned* __restrict__ gpay, const int* __restrict__ boff,
        int* __restrict__ rowptr, int* __restrict__ csr_src) {
    __shared__ int cnt[BKSZ];
    __shared__ int ts[256];
    const int b = blockIdx.x >> 2;
    const int sub = blockIdx.x & 3;
    const int tid = threadIdx.x;
    const int off = boff[b];
    const int blen = boff[b + 1] - off;
    const int d0 = b << BKB;
    for (int i = tid; i < BKSZ; i += 256) cnt[i] = 0;
    __syncthreads();
    for (int i = tid; i < blen; i += 256)
        atomicAdd(&cnt[gpay[off + i] >> 17], 1);
    __syncthreads();
    // in-place exclusive scan of cnt[2048]: 8 per thread + block scan
    int v[8], s = 0;
#pragma unroll
    for (int k = 0; k < 8; ++k) { v[k] = cnt[tid * 8 + k]; s += v[k]; }
    ts[tid] = s;
    __syncthreads();
    for (int o = 1; o < 256; o <<= 1) {
        int u = (tid >= o) ? ts[tid - o] : 0;
        __syncthreads();
        ts[tid] += u;
        __syncthreads();
    }
    int run = (tid == 0) ? 0 : ts[tid - 1];
#pragma unroll
    for (int k = 0; k < 8; ++k) { int c = v[k]; cnt[tid * 8 + k] = run; run += c; }
    __syncthreads();
    if (sub == 0) {
        for (int i = tid; i < BKSZ; i += 256) {
            int d = d0 + i;
            if (d < NN) rowptr[d] = off + cnt[i];
        }
        if (b == NBUCK - 1 && tid == 0) rowptr[NN] = ET;
    }
    __syncthreads();
    for (int i = tid; i < blen; i += 256) {
        unsigned pay = gpay[off + i];
        int rel = pay >> 17;
        if ((rel >> 9) == sub) {
            int pos = atomicAdd(&cnt[rel], 1);
            csr_src[off + pos] = (int)(pay & 0x1FFFFu);
        }
    }
}

// ---------- conv1 fused: softmax-agg + ReLU/bias + gemm2 + rec pack ------
__global__ __launch_bounds__(256) void conv1_fused_kernel(
        const int* __restrict__ rowptr, const int* __restrict__ csr_src,
        const float* __restrict__ as1, const float* __restrict__ ad1,
        const __half* __restrict__ h1, const float* __restrict__ b1,
        const float* __restrict__ W2, const float* __restrict__ as2,
        const float* __restrict__ ad2, float4* __restrict__ rec) {
    long gid = (long)blockIdx.x * 256 + threadIdx.x;
    int n = (int)(gid >> 6);
    if (n >= NN) return;
    n = __builtin_amdgcn_readfirstlane(n);   // wave-uniform -> scalar loads
    int c = threadIdx.x & 63;
    int h = c >> 3;
    float adh = ad1[n * 8 + h];
    int jb = rowptr[n], je = rowptr[n + 1];
    float l0 = 0.f, l1 = 0.f, l2 = 0.f, l3 = 0.f;
    float a0 = 0.f, a1 = 0.f, a2 = 0.f, a3 = 0.f;
    int j = jb;
    for (; j + 3 < je; j += 4) {
        int s0 = csr_src[j], s1 = csr_src[j + 1];
        int s2 = csr_src[j + 2], s3 = csr_src[j + 3];
        float p0 = __expf(leaky(as1[s0 * 8 + h] + adh));
        float p1 = __expf(leaky(as1[s1 * 8 + h] + adh));
        float p2 = __expf(leaky(as1[s2 * 8 + h] + adh));
        float p3 = __expf(leaky(as1[s3 * 8 + h] + adh));
        l0 += p0; l1 += p1; l2 += p2; l3 += p3;
        a0 += p0 * __half2float(h1[(long)s0 * 64 + c]);
        a1 += p1 * __half2float(h1[(long)s1 * 64 + c]);
        a2 += p2 * __half2float(h1[(long)s2 * 64 + c]);
        a3 += p3 * __half2float(h1[(long)s3 * 64 + c]);
    }
    for (; j < je; ++j) {
        int s = csr_src[j];
        float p = __expf(leaky(as1[s * 8 + h] + adh));
        l0 += p;
        a0 += p * __half2float(h1[(long)s * 64 + c]);
    }
    float l = (l0 + l1) + (l2 + l3);
    float acc = (a0 + a1) + (a2 + a3);
    float o = acc / (l + 1e-16f);
    float a = o + b1[c];
    a = a > 0.f ? a : 0.f;                 // ReLU
    float r0 = a * W2[c * 2];
    float r1 = a * W2[c * 2 + 1];
#pragma unroll
    for (int off = 32; off > 0; off >>= 1) {
        r0 += __shfl_xor(r0, off, 64);
        r1 += __shfl_xor(r1, off, 64);
    }
    if (c == 0) {
        float s2v = r0 * as2[0] + r1 * as2[1];
        float d2v = r0 * ad2[0] + r1 * ad2[1];
        rec[n] = make_float4(s2v, r0, r1, d2v);   // (as2o, h2_0, h2_1, ad2o)
    }
}

// ---------- conv2 fused with mean-pool (LDS partials) ----------
__global__ __launch_bounds__(256) void conv2_pool_kernel(
        const int* __restrict__ rowptr, const int* __restrict__ csr_src,
        const float4* __restrict__ rec, const int* __restrict__ batch,
        float* __restrict__ pooled /*128 sums + 64 counts*/) {
    __shared__ float ls[192];
    int tid = threadIdx.x;
    if (tid < 192) ls[tid] = 0.f;
    __syncthreads();
    int n = blockIdx.x * 256 + tid;
    if (n < NN) {
        float adn = rec[n].w;
        int jb = rowptr[n], je = rowptr[n + 1];
        float l0 = 0.f, l1 = 0.f, x0 = 0.f, x1 = 0.f, y0 = 0.f, y1 = 0.f;
        int j = jb;
        for (; j + 1 < je; j += 2) {
            float4 ra = rec[csr_src[j]];
            float4 rb = rec[csr_src[j + 1]];
            float pa = __expf(leaky(ra.x + adn));
            float pb = __expf(leaky(rb.x + adn));
            l0 += pa; x0 += pa * ra.y; y0 += pa * ra.z;
            l1 += pb; x1 += pb * rb.y; y1 += pb * rb.z;
        }
        for (; j < je; ++j) {
            float4 ra = rec[csr_src[j]];
            float pa = __expf(leaky(ra.x + adn));
            l0 += pa; x0 += pa * ra.y; y0 += pa * ra.z;
        }
        float inv = 1.f / (l0 + l1 + 1e-16f);
        int g = batch[n];
        atomicAdd(&ls[g * 2],     (x0 + x1) * inv);
        atomicAdd(&ls[g * 2 + 1], (y0 + y1) * inv);
        atomicAdd(&ls[128 + g],   1.f);
    }
    __syncthreads();
    if (tid < 192) atomicAdd(&pooled[tid], ls[tid]);
}

// ---------- finalize: mean, +b2, log_softmax ----------
__global__ __launch_bounds__(64) void final_kernel(
        const float* __restrict__ pooled, const float* __restrict__ b2,
        float* __restrict__ out) {
    int g = threadIdx.x;
    if (g >= 64) return;
    float c = pooled[128 + g];
    float denom = c > 1.f ? c : 1.f;
    float p0 = pooled[g * 2] / denom + b2[0];
    float p1 = pooled[g * 2 + 1] / denom + b2[1];
    float m = fmaxf(p0, p1);
    float lse = m + logf(expf(p0 - m) + expf(p1 - m));
    out[g * 2] = p0 - lse;
    out[g * 2 + 1] = p1 - lse;
}

extern "C" void kernel_launch(void* const* d_in, const int* in_sizes, int n_in,
                              void* d_out, int out_size, void* d_ws, size_t ws_size,
                              hipStream_t stream) {
    const float* x   = (const float*)d_in[0];
    const int*   ei  = (const int*)d_in[1];     // [2,E] int32
    const int*   bat = (const int*)d_in[2];     // [N]
    const float* W1  = (const float*)d_in[3];
    const float* as1 = (const float*)d_in[4];
    const float* ad1 = (const float*)d_in[5];
    const float* b1  = (const float*)d_in[6];
    const float* W2  = (const float*)d_in[7];
    const float* as2 = (const float*)d_in[8];
    const float* ad2 = (const float*)d_in[9];
    const float* b2  = (const float*)d_in[10];
    float* out = (float*)d_out;

    float* ws = (float*)d_ws;
    // workspace layout (element offsets; off_rec 16B-aligned)
    const long off_h1     = 0;                          // N*64 halves = N*32 f
    const long off_wt     = off_h1   + (long)NN * 32;   // 8192 halves = 4096 f
    const long off_as1    = off_wt   + 4096;            // N*8
    const long off_ad1    = off_as1  + (long)NN * 8;    // N*8
    const long off_rec    = off_ad1  + (long)NN * 8;    // N*4 (float4)
    const long off_rowptr = off_rec  + (long)NN * 4;    // N+1 (int)
    const long off_gpay   = off_rowptr + NN + 1;        // ET (uint)
    const long off_csr    = off_gpay + ET;              // ET (int)
    const long off_boff   = off_csr + ET;               // NBUCK+1 (int)
    const long off_bcur   = off_boff + NBUCK + 1;       // NBUCK*PAD (int)
    const long off_zero   = off_bcur + NBUCK * PAD;     // ---- zeroed ----
    const long off_bcnt   = off_zero;                   // NBUCK*PAD (int)
    const long off_pool   = off_bcnt + NBUCK * PAD;     // 192
    const long zero_elems = off_pool + 192 - off_zero;

    hipMemsetAsync(ws + off_zero, 0, zero_elems * sizeof(float), stream);

    convert_w_kernel<<<32, 256, 0, stream>>>(W1, (f16*)(ws + off_wt));
    gemm1_mfma<<<(NN + 63) / 64, 256, 0, stream>>>(
        x, (const f16*)(ws + off_wt), (__half*)(ws + off_h1));
    alpha1_kernel<<<(NN * 8 + 255) / 256, 256, 0, stream>>>(
        (const __half*)(ws + off_h1), as1, ad1, ws + off_as1, ws + off_ad1);

    bucket_count<<<NCH2, 256, 0, stream>>>(ei, (int*)(ws + off_bcnt));
    bucket_scan<<<1, 64, 0, stream>>>((const int*)(ws + off_bcnt),
                                      (int*)(ws + off_boff),
                                      (int*)(ws + off_bcur));
    bucket_fill<<<NCH2, 256, 0, stream>>>(ei, (int*)(ws + off_bcur),
                                          (unsigned*)(ws + off_gpay));
    fine_csr<<<NBUCK * SUBN, 256, 0, stream>>>(
        (const unsigned*)(ws + off_gpay), (const int*)(ws + off_boff),
        (int*)(ws + off_rowptr), (int*)(ws + off_csr));

    conv1_fused_kernel<<<(int)(((long)NN * 64 + 255) / 256), 256, 0, stream>>>(
        (const int*)(ws + off_rowptr), (const int*)(ws + off_csr),
        ws + off_as1, ws + off_ad1, (const __half*)(ws + off_h1), b1, W2,
        as2, ad2, (float4*)(ws + off_rec));

    conv2_pool_kernel<<<(NN + 255) / 256, 256, 0, stream>>>(
        (const int*)(ws + off_rowptr), (const int*)(ws + off_csr),
        (const float4*)(ws + off_rec), bat, ws + off_pool);

    final_kernel<<<1, 64, 0, stream>>>(ws + off_pool, b2, out);
}

// Round 9
// 287.589 us; speedup vs baseline: 5.4750x; 1.1690x over previous
//
#include <hip/hip_runtime.h>
#include <hip/hip_bf16.h>
#include <hip/hip_fp16.h>
#include <math.h>

// Problem constants
#define NN 100000
#define EE 1600000
#define ET 1700000            // E + N self-loops
#define NEG_SLOPE 0.2f
#define XS_STRIDE 136         // 128 + 8 halves: kills LDS bank conflicts

// bucket-sort CSR build
#define BKB 8                 // log2(dsts per bucket)
#define BKSZ 256
#define NBUCK 391             // ceil(NN / BKSZ)
#define PAD 32                // ints per counter (one 128B line each)
#define EPT2 16
#define CHUNK2 (256 * EPT2)   // 4096 edges per block
#define NCH2 ((ET + CHUNK2 - 1) / CHUNK2)   // 416

typedef _Float16 f16;
typedef f16 f16x8 __attribute__((ext_vector_type(8)));
typedef float f32x4 __attribute__((ext_vector_type(4)));

__device__ __forceinline__ float leaky(float v) {
    return v > 0.f ? v : NEG_SLOPE * v;
}

// ---------- W1 fp32 [128][64] -> wt fp16 [64][128] (transposed) ----------
__global__ __launch_bounds__(256) void convert_w_kernel(
        const float* __restrict__ W1, f16* __restrict__ wt) {
    int i = blockIdx.x * 256 + threadIdx.x;
    if (i < 128 * 64) {
        int n = i >> 7, k = i & 127;
        wt[n * 128 + k] = (f16)W1[k * 64 + n];
    }
}

// ---------- GEMM1 via MFMA ----------
__global__ __launch_bounds__(256) void gemm1_mfma(
        const float* __restrict__ x, const f16* __restrict__ wt,
        __half* __restrict__ h1) {
    __shared__ f16 xs[64 * XS_STRIDE];
    const int tid = threadIdx.x;
    const int node0 = blockIdx.x * 64;
    for (int i = tid; i < 64 * 64; i += 256) {
        int r = i >> 6, cp = i & 63;
        int n = node0 + r;
        float2 v = (n < NN) ? ((const float2*)x)[(long)n * 64 + cp]
                            : make_float2(0.f, 0.f);
        xs[r * XS_STRIDE + 2 * cp]     = (f16)v.x;
        xs[r * XS_STRIDE + 2 * cp + 1] = (f16)v.y;
    }
    __syncthreads();
    const int wv = tid >> 6;
    const int lane = tid & 63;
    const int n16 = lane & 15;
    const int quad = lane >> 4;
    f16x8 bf[4][4];
#pragma unroll
    for (int t = 0; t < 4; ++t)
#pragma unroll
        for (int kk = 0; kk < 4; ++kk)
            bf[t][kk] = *(const f16x8*)(wt + ((t * 16 + n16) * 128 + kk * 32 + quad * 8));
    f32x4 acc[4] = {{0,0,0,0},{0,0,0,0},{0,0,0,0},{0,0,0,0}};
#pragma unroll
    for (int kk = 0; kk < 4; ++kk) {
        f16x8 af = *(const f16x8*)(xs + ((wv * 16 + n16) * XS_STRIDE + kk * 32 + quad * 8));
#pragma unroll
        for (int t = 0; t < 4; ++t)
            acc[t] = __builtin_amdgcn_mfma_f32_16x16x32_f16(af, bf[t][kk], acc[t], 0, 0, 0);
    }
#pragma unroll
    for (int t = 0; t < 4; ++t)
#pragma unroll
        for (int r = 0; r < 4; ++r) {
            int m = node0 + wv * 16 + quad * 4 + r;
            if (m < NN) h1[(long)m * 64 + t * 16 + n16] = __float2half_rn(acc[t][r]);
        }
}

// ---------- alpha1 ----------
__global__ __launch_bounds__(256) void alpha1_kernel(
        const __half* __restrict__ h1, const float* __restrict__ att_s,
        const float* __restrict__ att_d,
        float* __restrict__ alpha_s, float* __restrict__ alpha_d) {
    int i = blockIdx.x * 256 + threadIdx.x;   // i = node*8 + head
    if (i >= NN * 8) return;
    int h = i & 7;
    const __half* hp = h1 + (long)i * 8;
    float s = 0.f, d = 0.f;
#pragma unroll
    for (int c = 0; c < 8; ++c) {
        float v = __half2float(hp[c]);
        s += v * att_s[h * 8 + c];
        d += v * att_d[h * 8 + c];
    }
    alpha_s[i] = s;
    alpha_d[i] = d;
}

// ---------- B1: coarse bucket count (LDS hist -> padded global atomics) ---
__global__ __launch_bounds__(256) void bucket_count(
        const int* __restrict__ ei, int* __restrict__ bcnt) {
    __shared__ int lcnt[NBUCK];
    const int tid = threadIdx.x;
    for (int i = tid; i < NBUCK; i += 256) lcnt[i] = 0;
    __syncthreads();
    const int base = blockIdx.x * CHUNK2 + tid;
#pragma unroll
    for (int k = 0; k < EPT2; ++k) {
        int e = base + k * 256;
        if (e >= ET) break;
        int d = (e < EE) ? __builtin_nontemporal_load(ei + EE + e) : (e - EE);
        atomicAdd(&lcnt[d >> BKB], 1);
    }
    __syncthreads();
    for (int i = tid; i < NBUCK; i += 256)
        if (lcnt[i]) atomicAdd(&bcnt[i * PAD], lcnt[i]);
}

// ---------- B2: exclusive scan of 391 bucket counts (1 block) ----------
__global__ __launch_bounds__(512) void bucket_scan(
        const int* __restrict__ bcnt, int* __restrict__ boff,
        int* __restrict__ bcur) {
    __shared__ int sh[512];
    int t = threadIdx.x;
    int v = (t < NBUCK) ? bcnt[t * PAD] : 0;
    sh[t] = v;
    __syncthreads();
    for (int off = 1; off < 512; off <<= 1) {
        int u = (t >= off) ? sh[t - off] : 0;
        __syncthreads();
        sh[t] += u;
        __syncthreads();
    }
    if (t < NBUCK) {
        boff[t] = sh[t] - v;
        bcur[t * PAD] = sh[t] - v;
        if (t == NBUCK - 1) boff[NBUCK] = sh[t];
    }
}

// ---------- B3: bucket fill — packed payload rel<<17|src ----------
__global__ __launch_bounds__(256) void bucket_fill(
        const int* __restrict__ ei, int* __restrict__ bcur,
        unsigned* __restrict__ gpay) {
    __shared__ int lcnt[NBUCK];
    __shared__ int gbase[NBUCK];
    const int tid = threadIdx.x;
    for (int i = tid; i < NBUCK; i += 256) lcnt[i] = 0;
    __syncthreads();
    const int base = blockIdx.x * CHUNK2 + tid;
    unsigned pay[EPT2];
    int bk[EPT2], pos[EPT2];
#pragma unroll
    for (int k = 0; k < EPT2; ++k) {
        int e = base + k * 256;
        if (e < ET) {
            int s, d;
            if (e < EE) {
                s = __builtin_nontemporal_load(ei + e);
                d = __builtin_nontemporal_load(ei + EE + e);
            } else { s = d = e - EE; }
            int b = d >> BKB;
            bk[k] = b;
            pay[k] = ((unsigned)(d & (BKSZ - 1)) << 17) | (unsigned)s;
            pos[k] = atomicAdd(&lcnt[b], 1);
        } else bk[k] = -1;
    }
    __syncthreads();
    for (int i = tid; i < NBUCK; i += 256)
        gbase[i] = lcnt[i] ? atomicAdd(&bcur[i * PAD], lcnt[i]) : 0;
    __syncthreads();
#pragma unroll
    for (int k = 0; k < EPT2; ++k)
        if (bk[k] >= 0) gpay[gbase[bk[k]] + pos[k]] = pay[k];
}

// ---------- B4: fine CSR within each bucket (one block per bucket) --------
__global__ __launch_bounds__(256) void fine_csr(
        const unsigned* __restrict__ gpay, const int* __restrict__ boff,
        int* __restrict__ rowptr, int* __restrict__ csr_src) {
    __shared__ int cnt[BKSZ];     // 256: hist -> cursors
    __shared__ int ts[256];
    const int b = blockIdx.x;
    const int tid = threadIdx.x;
    const int off = boff[b];
    const int blen = boff[b + 1] - off;
    const int d0 = b << BKB;
    cnt[tid] = 0;
    __syncthreads();
    for (int i = tid; i < blen; i += 256)
        atomicAdd(&cnt[gpay[off + i] >> 17], 1);
    __syncthreads();
    int v = cnt[tid];
    ts[tid] = v;
    __syncthreads();
    for (int o = 1; o < 256; o <<= 1) {
        int u = (tid >= o) ? ts[tid - o] : 0;
        __syncthreads();
        ts[tid] += u;
        __syncthreads();
    }
    int excl = ts[tid] - v;
    cnt[tid] = excl;              // cursor = exclusive offset
    int d = d0 + tid;
    if (d < NN) rowptr[d] = off + excl;
    if (b == NBUCK - 1 && tid == 0) rowptr[NN] = ET;
    __syncthreads();
    for (int i = tid; i < blen; i += 256) {
        unsigned pay = gpay[off + i];
        int pos = atomicAdd(&cnt[pay >> 17], 1);
        csr_src[off + pos] = (int)(pay & 0x1FFFFu);
    }
}

// ---------- conv1 fused: softmax-agg + ReLU/bias + gemm2 + rec pack ------
__global__ __launch_bounds__(256) void conv1_fused_kernel(
        const int* __restrict__ rowptr, const int* __restrict__ csr_src,
        const float* __restrict__ as1, const float* __restrict__ ad1,
        const __half* __restrict__ h1, const float* __restrict__ b1,
        const float* __restrict__ W2, const float* __restrict__ as2,
        const float* __restrict__ ad2, float4* __restrict__ rec) {
    long gid = (long)blockIdx.x * 256 + threadIdx.x;
    int n = (int)(gid >> 6);
    if (n >= NN) return;
    n = __builtin_amdgcn_readfirstlane(n);   // wave-uniform -> scalar loads
    int c = threadIdx.x & 63;
    int h = c >> 3;
    float adh = ad1[n * 8 + h];
    int jb = rowptr[n], je = rowptr[n + 1];
    float l0 = 0.f, l1 = 0.f, l2 = 0.f, l3 = 0.f;
    float a0 = 0.f, a1 = 0.f, a2 = 0.f, a3 = 0.f;
    int j = jb;
    for (; j + 3 < je; j += 4) {
        int s0 = csr_src[j], s1 = csr_src[j + 1];
        int s2 = csr_src[j + 2], s3 = csr_src[j + 3];
        float p0 = __expf(leaky(as1[s0 * 8 + h] + adh));
        float p1 = __expf(leaky(as1[s1 * 8 + h] + adh));
        float p2 = __expf(leaky(as1[s2 * 8 + h] + adh));
        float p3 = __expf(leaky(as1[s3 * 8 + h] + adh));
        l0 += p0; l1 += p1; l2 += p2; l3 += p3;
        a0 += p0 * __half2float(h1[(long)s0 * 64 + c]);
        a1 += p1 * __half2float(h1[(long)s1 * 64 + c]);
        a2 += p2 * __half2float(h1[(long)s2 * 64 + c]);
        a3 += p3 * __half2float(h1[(long)s3 * 64 + c]);
    }
    for (; j < je; ++j) {
        int s = csr_src[j];
        float p = __expf(leaky(as1[s * 8 + h] + adh));
        l0 += p;
        a0 += p * __half2float(h1[(long)s * 64 + c]);
    }
    float l = (l0 + l1) + (l2 + l3);
    float acc = (a0 + a1) + (a2 + a3);
    float o = acc / (l + 1e-16f);
    float a = o + b1[c];
    a = a > 0.f ? a : 0.f;                 // ReLU
    float r0 = a * W2[c * 2];
    float r1 = a * W2[c * 2 + 1];
#pragma unroll
    for (int off = 32; off > 0; off >>= 1) {
        r0 += __shfl_xor(r0, off, 64);
        r1 += __shfl_xor(r1, off, 64);
    }
    if (c == 0) {
        float s2v = r0 * as2[0] + r1 * as2[1];
        float d2v = r0 * ad2[0] + r1 * ad2[1];
        rec[n] = make_float4(s2v, r0, r1, d2v);   // (as2o, h2_0, h2_1, ad2o)
    }
}

// ---------- conv2 fused with mean-pool (LDS partials) ----------
__global__ __launch_bounds__(256) void conv2_pool_kernel(
        const int* __restrict__ rowptr, const int* __restrict__ csr_src,
        const float4* __restrict__ rec, const int* __restrict__ batch,
        float* __restrict__ pooled /*128 sums + 64 counts*/) {
    __shared__ float ls[192];
    int tid = threadIdx.x;
    if (tid < 192) ls[tid] = 0.f;
    __syncthreads();
    int n = blockIdx.x * 256 + tid;
    if (n < NN) {
        float adn = rec[n].w;
        int jb = rowptr[n], je = rowptr[n + 1];
        float l0 = 0.f, l1 = 0.f, x0 = 0.f, x1 = 0.f, y0 = 0.f, y1 = 0.f;
        int j = jb;
        for (; j + 1 < je; j += 2) {
            float4 ra = rec[csr_src[j]];
            float4 rb = rec[csr_src[j + 1]];
            float pa = __expf(leaky(ra.x + adn));
            float pb = __expf(leaky(rb.x + adn));
            l0 += pa; x0 += pa * ra.y; y0 += pa * ra.z;
            l1 += pb; x1 += pb * rb.y; y1 += pb * rb.z;
        }
        for (; j < je; ++j) {
            float4 ra = rec[csr_src[j]];
            float pa = __expf(leaky(ra.x + adn));
            l0 += pa; x0 += pa * ra.y; y0 += pa * ra.z;
        }
        float inv = 1.f / (l0 + l1 + 1e-16f);
        int g = batch[n];
        atomicAdd(&ls[g * 2],     (x0 + x1) * inv);
        atomicAdd(&ls[g * 2 + 1], (y0 + y1) * inv);
        atomicAdd(&ls[128 + g],   1.f);
    }
    __syncthreads();
    if (tid < 192) atomicAdd(&pooled[tid], ls[tid]);
}

// ---------- finalize: mean, +b2, log_softmax ----------
__global__ __launch_bounds__(64) void final_kernel(
        const float* __restrict__ pooled, const float* __restrict__ b2,
        float* __restrict__ out) {
    int g = threadIdx.x;
    if (g >= 64) return;
    float c = pooled[128 + g];
    float denom = c > 1.f ? c : 1.f;
    float p0 = pooled[g * 2] / denom + b2[0];
    float p1 = pooled[g * 2 + 1] / denom + b2[1];
    float m = fmaxf(p0, p1);
    float lse = m + logf(expf(p0 - m) + expf(p1 - m));
    out[g * 2] = p0 - lse;
    out[g * 2 + 1] = p1 - lse;
}

extern "C" void kernel_launch(void* const* d_in, const int* in_sizes, int n_in,
                              void* d_out, int out_size, void* d_ws, size_t ws_size,
                              hipStream_t stream) {
    const float* x   = (const float*)d_in[0];
    const int*   ei  = (const int*)d_in[1];     // [2,E] int32
    const int*   bat = (const int*)d_in[2];     // [N]
    const float* W1  = (const float*)d_in[3];
    const float* as1 = (const float*)d_in[4];
    const float* ad1 = (const float*)d_in[5];
    const float* b1  = (const float*)d_in[6];
    const float* W2  = (const float*)d_in[7];
    const float* as2 = (const float*)d_in[8];
    const float* ad2 = (const float*)d_in[9];
    const float* b2  = (const float*)d_in[10];
    float* out = (float*)d_out;

    float* ws = (float*)d_ws;
    // workspace layout (element offsets; off_rec 16B-aligned)
    const long off_h1     = 0;                          // N*64 halves = N*32 f
    const long off_wt     = off_h1   + (long)NN * 32;   // 8192 halves = 4096 f
    const long off_as1    = off_wt   + 4096;            // N*8
    const long off_ad1    = off_as1  + (long)NN * 8;    // N*8
    const long off_rec    = off_ad1  + (long)NN * 8;    // N*4 (float4)
    const long off_rowptr = off_rec  + (long)NN * 4;    // N+1 (int)
    const long off_gpay   = off_rowptr + NN + 1;        // ET (uint)
    const long off_csr    = off_gpay + ET;              // ET (int)
    const long off_boff   = off_csr + ET;               // NBUCK+1 (int)
    const long off_bcur   = off_boff + NBUCK + 1;       // NBUCK*PAD (int)
    const long off_zero   = off_bcur + NBUCK * PAD;     // ---- zeroed ----
    const long off_bcnt   = off_zero;                   // NBUCK*PAD (int)
    const long off_pool   = off_bcnt + NBUCK * PAD;     // 192
    const long zero_elems = off_pool + 192 - off_zero;

    hipMemsetAsync(ws + off_zero, 0, zero_elems * sizeof(float), stream);

    convert_w_kernel<<<32, 256, 0, stream>>>(W1, (f16*)(ws + off_wt));
    gemm1_mfma<<<(NN + 63) / 64, 256, 0, stream>>>(
        x, (const f16*)(ws + off_wt), (__half*)(ws + off_h1));
    alpha1_kernel<<<(NN * 8 + 255) / 256, 256, 0, stream>>>(
        (const __half*)(ws + off_h1), as1, ad1, ws + off_as1, ws + off_ad1);

    bucket_count<<<NCH2, 256, 0, stream>>>(ei, (int*)(ws + off_bcnt));
    bucket_scan<<<1, 512, 0, stream>>>((const int*)(ws + off_bcnt),
                                       (int*)(ws + off_boff),
                                       (int*)(ws + off_bcur));
    bucket_fill<<<NCH2, 256, 0, stream>>>(ei, (int*)(ws + off_bcur),
                                          (unsigned*)(ws + off_gpay));
    fine_csr<<<NBUCK, 256, 0, stream>>>(
        (const unsigned*)(ws + off_gpay), (const int*)(ws + off_boff),
        (int*)(ws + off_rowptr), (int*)(ws + off_csr));

    conv1_fused_kernel<<<(int)(((long)NN * 64 + 255) / 256), 256, 0, stream>>>(
        (const int*)(ws + off_rowptr), (const int*)(ws + off_csr),
        ws + off_as1, ws + off_ad1, (const __half*)(ws + off_h1), b1, W2,
        as2, ad2, (float4*)(ws + off_rec));

    conv2_pool_kernel<<<(NN + 255) / 256, 256, 0, stream>>>(
        (const int*)(ws + off_rowptr), (const int*)(ws + off_csr),
        (const float4*)(ws + off_rec), bat, ws + off_pool);

    final_kernel<<<1, 64, 0, stream>>>(ws + off_pool, b2, out);
}